// Round 7
// baseline (1434.234 us; speedup 1.0000x reference)
//
#include <hip/hip_runtime.h>
#include <math.h>
#include <limits.h>

namespace {
constexpr int NV = 3;    // views
constexpr int NC = 16;   // channels
constexpr int ND = 32;   // depths
constexpr int NH = 256;
constexpr int NW = 320;
constexpr int HW = NH * NW;       // 81920
constexpr int DG = 8;             // depths per thread
}

// ---------------------------------------------------------------------------
// Setup: proj_v = P_v @ inv(P_0); store rot(9)+trans(3) per src view.
// ---------------------------------------------------------------------------
__global__ void proj_setup_kernel(const float* __restrict__ pm,
                                  float* __restrict__ mats) {
    if (threadIdx.x != 0 || blockIdx.x != 0) return;
    float P[NV][4][4];
    for (int v = 0; v < NV; ++v) {
        const float* E = pm + v * 2 * 16;
        const float* K = pm + v * 2 * 16 + 16;
        for (int i = 0; i < 4; ++i)
            for (int j = 0; j < 4; ++j)
                P[v][i][j] = E[i * 4 + j];
        for (int i = 0; i < 3; ++i)
            for (int j = 0; j < 4; ++j) {
                float acc = 0.f;
                for (int k = 0; k < 3; ++k) acc += K[i * 4 + k] * E[k * 4 + j];
                P[v][i][j] = acc;
            }
    }
    float A[4][8];
    for (int i = 0; i < 4; ++i)
        for (int j = 0; j < 4; ++j) {
            A[i][j] = P[0][i][j];
            A[i][j + 4] = (i == j) ? 1.f : 0.f;
        }
    for (int col = 0; col < 4; ++col) {
        int piv = col;
        float best = fabsf(A[col][col]);
        for (int r = col + 1; r < 4; ++r) {
            float av = fabsf(A[r][col]);
            if (av > best) { best = av; piv = r; }
        }
        if (piv != col)
            for (int j = 0; j < 8; ++j) {
                float t = A[col][j]; A[col][j] = A[piv][j]; A[piv][j] = t;
            }
        float inv = 1.f / A[col][col];
        for (int j = 0; j < 8; ++j) A[col][j] *= inv;
        for (int r = 0; r < 4; ++r) {
            if (r == col) continue;
            float f = A[r][col];
            if (f != 0.f)
                for (int j = 0; j < 8; ++j) A[r][j] -= f * A[col][j];
        }
    }
    float Inv[4][4];
    for (int i = 0; i < 4; ++i)
        for (int j = 0; j < 4; ++j) Inv[i][j] = A[i][j + 4];

    for (int v = 1; v < NV; ++v) {
        float M[4][4];
        for (int i = 0; i < 4; ++i)
            for (int j = 0; j < 4; ++j) {
                float acc = 0.f;
                for (int k = 0; k < 4; ++k) acc += P[v][i][k] * Inv[k][j];
                M[i][j] = acc;
            }
        float* o = mats + (v - 1) * 12;
        for (int i = 0; i < 3; ++i)
            for (int j = 0; j < 3; ++j) o[i * 3 + j] = M[i][j];
        for (int i = 0; i < 3; ++i) o[9 + i] = M[i][3];
    }
}

// ---------------------------------------------------------------------------
// Cost volume R7. One thread per (pixel, 8-depth group); depths looped
// in-register. The 2x2 bilinear window per (view, channel-chunk) is gathered
// once and MEMOIZED across the depth loop: reload only when (x0,y0) changes
// (per-lane divergent reload -> exact for arbitrary homographies; for
// slowly-varying warps the reload happens ~once). Cuts gather count ~8x vs
// the (d,n)-per-thread R4 (which was latency-bound: VALU busy 26us of 57us,
// the rest memory stall). Channels processed in 2 chunks of 8 to keep
// win[2][8][4]=64 VGPR bounded. All arrays statically indexed (full unroll).
// ---------------------------------------------------------------------------
__global__ __launch_bounds__(256, 4) void cost_kernel7(
    const float* __restrict__ feats,   // [V][C][HW]
    const float* __restrict__ dvals,   // [D][HW]
    const float* __restrict__ wreg,    // [C]
    const float* __restrict__ mats,    // [2][12]
    float* __restrict__ cost)          // [D][HW]
{
    const int d0 = blockIdx.y * DG;
    const unsigned n = blockIdx.x * 256u + threadIdx.x;
    const int y = (int)(n / NW);
    const int x = (int)(n - (unsigned)y * NW);
    const float fx = (float)x, fy = (float)y;
    const unsigned voff = n * 4u;

    // per-view rot*(x,y,1) and translation, hoisted (uniform mats -> s_loads)
    float rxv[2], ryv[2], rzv[2], t0v[2], t1v[2], t2v[2];
#pragma unroll
    for (int v = 0; v < 2; ++v) {
        const float* m = mats + v * 12;
        rxv[v] = fmaf(m[0], fx, fmaf(m[1], fy, m[2]));
        ryv[v] = fmaf(m[3], fx, fmaf(m[4], fy, m[5]));
        rzv[v] = fmaf(m[6], fx, fmaf(m[7], fy, m[8]));
        t0v[v] = m[9]; t1v[v] = m[10]; t2v[v] = m[11];
    }

    float costacc[DG];
#pragma unroll
    for (int dd = 0; dd < DG; ++dd) costacc[dd] = 0.f;

#pragma unroll
    for (int ch = 0; ch < 2; ++ch) {
        const int cbase = ch * 8;

        float rf[8];
#pragma unroll
        for (int c = 0; c < 8; ++c)
            rf[c] = *(const float*)((const char*)feats +
                                    (size_t)(cbase + c) * HW * 4 + voff);

        float win[2][8][4];        // memoized bilinear windows (regs)
        int kx[2] = {INT_MIN, INT_MIN};
        int ky[2] = {INT_MIN, INT_MIN};

#pragma unroll
        for (int dd = 0; dd < DG; ++dd) {
            const float depth = *(const float*)((const char*)dvals +
                                 (size_t)(d0 + dd) * HW * 4 + voff);

            float sum[8], sq[8];
#pragma unroll
            for (int c = 0; c < 8; ++c) {
                sum[c] = rf[c];
                sq[c] = rf[c] * rf[c];
            }

#pragma unroll
            for (int v = 0; v < 2; ++v) {
                float pxn = fmaf(rxv[v], depth, t0v[v]);
                float pyn = fmaf(ryv[v], depth, t1v[v]);
                float z   = fmaf(rzv[v], depth, t2v[v]);
                z = (fabsf(z) < 1e-6f) ? 1e-6f : z;
                float r0 = __builtin_amdgcn_rcpf(z);
                r0 = r0 * (2.0f - z * r0);          // Newton refine
                float px = pxn * r0, py = pyn * r0;
                float x0f = floorf(px), y0f = floorf(py);
                float wx = px - x0f, wy = py - y0f;
                int x0 = (int)x0f, y0 = (int)y0f;

                if (x0 != kx[v] || y0 != ky[v]) {   // window changed: reload
                    kx[v] = x0; ky[v] = y0;
                    int cx0 = min(max(x0, 0), NW - 1);
                    int cx1 = min(max(x0 + 1, 0), NW - 1);
                    int cy0 = min(max(y0, 0), NH - 1);
                    int cy1 = min(max(y0 + 1, 0), NH - 1);
                    unsigned o00 = (unsigned)(cy0 * NW + cx0) * 4u;
                    unsigned o01 = (unsigned)(cy0 * NW + cx1) * 4u;
                    unsigned o10 = (unsigned)(cy1 * NW + cx0) * 4u;
                    unsigned o11 = (unsigned)(cy1 * NW + cx1) * 4u;
                    const char* fvb =
                        (const char*)(feats + (size_t)(v + 1) * NC * HW);
#pragma unroll
                    for (int c = 0; c < 8; ++c) {
                        const char* fcb = fvb + (size_t)(cbase + c) * HW * 4;
                        win[v][c][0] = *(const float*)(fcb + o00);
                        win[v][c][1] = *(const float*)(fcb + o01);
                        win[v][c][2] = *(const float*)(fcb + o10);
                        win[v][c][3] = *(const float*)(fcb + o11);
                    }
                }

                bool vx0 = (x0 >= 0) && (x0 < NW);
                bool vx1 = (x0 + 1 >= 0) && (x0 + 1 < NW);
                bool vy0 = (y0 >= 0) && (y0 < NH);
                bool vy1 = (y0 + 1 >= 0) && (y0 + 1 < NH);
                float w00 = (1.f - wx) * (1.f - wy) * ((vx0 && vy0) ? 1.f : 0.f);
                float w01 = wx * (1.f - wy) * ((vx1 && vy0) ? 1.f : 0.f);
                float w10 = (1.f - wx) * wy * ((vx0 && vy1) ? 1.f : 0.f);
                float w11 = wx * wy * ((vx1 && vy1) ? 1.f : 0.f);

#pragma unroll
                for (int c = 0; c < 8; ++c) {
                    float val = fmaf(win[v][c][0], w00,
                                fmaf(win[v][c][1], w01,
                                fmaf(win[v][c][2], w10, win[v][c][3] * w11)));
                    sum[c] += val;
                    sq[c] = fmaf(val, val, sq[c]);
                }
            }

            float cst = 0.f;
            const float invV = 1.f / 3.f;
#pragma unroll
            for (int c = 0; c < 8; ++c) {
                float s = sum[c] * invV;
                float var = fmaf(sq[c], invV, -(s * s));
                cst = fmaf(var, wreg[cbase + c], cst);
            }
            costacc[dd] += cst;
        }
    }

#pragma unroll
    for (int dd = 0; dd < DG; ++dd)
        *(float*)((char*)cost + (size_t)(d0 + dd) * HW * 4 + voff) = costacc[dd];
}

// ---------------------------------------------------------------------------
// Softmax over D + depth regression + confidence (reads cost from prob
// region of d_out, overwrites with prob).
// ---------------------------------------------------------------------------
__global__ __launch_bounds__(256) void softmax_kernel(
    const float* __restrict__ dvals,
    float* __restrict__ out)
{
    int n = blockIdx.x * blockDim.x + threadIdx.x;
    float* prob = out + 2 * HW;

    float c[ND];
    float mx = -INFINITY;
#pragma unroll
    for (int d = 0; d < ND; ++d) {
        c[d] = prob[d * HW + n];
        mx = fmaxf(mx, c[d]);
    }
    float ssum = 0.f;
#pragma unroll
    for (int d = 0; d < ND; ++d) {
        float e = expf(c[d] - mx);
        c[d] = e;
        ssum += e;
    }
    float inv = 1.f / ssum;
    float depth_acc = 0.f, didx_acc = 0.f;
#pragma unroll
    for (int d = 0; d < ND; ++d) {
        float pv = c[d] * inv;
        c[d] = pv;
        prob[d * HW + n] = pv;
        depth_acc += pv * dvals[d * HW + n];
        didx_acc += pv * (float)d;
    }
    int di = (int)didx_acc;            // trunc toward zero, matches astype(int32)
    di = min(max(di, 0), ND - 1);
    float pdi = 0.f, pdi1 = 0.f;
#pragma unroll
    for (int d = 0; d < ND; ++d) {
        pdi = (d == di) ? c[d] : pdi;
        pdi1 = (d == di + 1) ? c[d] : pdi1;
    }
    out[n] = depth_acc;
    out[HW + n] = pdi + pdi1;
}

extern "C" void kernel_launch(void* const* d_in, const int* in_sizes, int n_in,
                              void* d_out, int out_size, void* d_ws, size_t ws_size,
                              hipStream_t stream) {
    const float* feats = (const float*)d_in[0];
    const float* pm    = (const float*)d_in[1];
    const float* dvals = (const float*)d_in[2];
    const float* wreg  = (const float*)d_in[3];
    float* out = (float*)d_out;
    float* mats = (float*)d_ws;                  // 24 floats

    proj_setup_kernel<<<1, 64, 0, stream>>>(pm, mats);
    cost_kernel7<<<dim3(HW / 256, ND / DG), 256, 0, stream>>>(
        feats, dvals, wreg, mats, out + 2 * HW);
    softmax_kernel<<<HW / 256, 256, 0, stream>>>(dvals, out);
}

// Round 8
// 67.534 us; speedup vs baseline: 21.2373x; 21.2373x over previous
//
#include <hip/hip_runtime.h>
#include <math.h>

namespace {
constexpr int NV = 3;    // views
constexpr int NC = 16;   // channels
constexpr int ND = 32;   // depths
constexpr int NH = 256;
constexpr int NW = 320;
constexpr int HW = NH * NW;       // 81920
constexpr int DG = 8;             // depths per thread
// symmetric 4x4 index (i<=j): 0..9
#define SYM(i, j) ((i) * 4 + (j) - (i) * ((i) + 1) / 2)
}

// ---------------------------------------------------------------------------
// Setup: proj_v = P_v @ inv(P_0); store rot(9)+trans(3) per src view.
// ---------------------------------------------------------------------------
__global__ void proj_setup_kernel(const float* __restrict__ pm,
                                  float* __restrict__ mats) {
    if (threadIdx.x != 0 || blockIdx.x != 0) return;
    float P[NV][4][4];
    for (int v = 0; v < NV; ++v) {
        const float* E = pm + v * 2 * 16;
        const float* K = pm + v * 2 * 16 + 16;
        for (int i = 0; i < 4; ++i)
            for (int j = 0; j < 4; ++j)
                P[v][i][j] = E[i * 4 + j];
        for (int i = 0; i < 3; ++i)
            for (int j = 0; j < 4; ++j) {
                float acc = 0.f;
                for (int k = 0; k < 3; ++k) acc += K[i * 4 + k] * E[k * 4 + j];
                P[v][i][j] = acc;
            }
    }
    float A[4][8];
    for (int i = 0; i < 4; ++i)
        for (int j = 0; j < 4; ++j) {
            A[i][j] = P[0][i][j];
            A[i][j + 4] = (i == j) ? 1.f : 0.f;
        }
    for (int col = 0; col < 4; ++col) {
        int piv = col;
        float best = fabsf(A[col][col]);
        for (int r = col + 1; r < 4; ++r) {
            float av = fabsf(A[r][col]);
            if (av > best) { best = av; piv = r; }
        }
        if (piv != col)
            for (int j = 0; j < 8; ++j) {
                float t = A[col][j]; A[col][j] = A[piv][j]; A[piv][j] = t;
            }
        float inv = 1.f / A[col][col];
        for (int j = 0; j < 8; ++j) A[col][j] *= inv;
        for (int r = 0; r < 4; ++r) {
            if (r == col) continue;
            float f = A[r][col];
            if (f != 0.f)
                for (int j = 0; j < 8; ++j) A[r][j] -= f * A[col][j];
        }
    }
    float Inv[4][4];
    for (int i = 0; i < 4; ++i)
        for (int j = 0; j < 4; ++j) Inv[i][j] = A[i][j + 4];

    for (int v = 1; v < NV; ++v) {
        float M[4][4];
        for (int i = 0; i < 4; ++i)
            for (int j = 0; j < 4; ++j) {
                float acc = 0.f;
                for (int k = 0; k < 4; ++k) acc += P[v][i][k] * Inv[k][j];
                M[i][j] = acc;
            }
        float* o = mats + (v - 1) * 12;
        for (int i = 0; i < 3; ++i)
            for (int j = 0; j < 3; ++j) o[i * 3 + j] = M[i][j];
        for (int i = 0; i < 3; ++i) o[9 + i] = M[i][3];
    }
}

// ---------------------------------------------------------------------------
// Cost volume R8. One thread per (pixel, 8-depth group). The bilinear window
// (x0,y0) per view is computed UNCONDITIONALLY from the group's first depth
// (R7's conditionally-updated window array was demoted to scratch: 1.4 GB
// spill traffic). The 16 channels are streamed ONCE into 45 quadratic-form
// accumulators:
//   cost(d) = (2/9) [ r2 + a'G1 a + b'G2 b - R1'a - R2'b - a'C b ]
// where only the 8 bilinear weights (a,b) depend on depth -> per-depth work
// is ~110 VALU and ZERO loads. Per-lane slow path (direct gather, same
// algebra) preserves exactness for arbitrary inputs; it is skipped via
// s_cbranch_execz when no lane's window deviates from the d0 window.
// IEEE division for px,py (NOT rcpf): bitwise-identical sampling positions
// vs the reference protect a razor-edge floor() pixel (rcpf caused the
// 2.4e-4 -> 4.0 absmax jump in R2).
// ---------------------------------------------------------------------------
__global__ __launch_bounds__(256) void cost_kernel8(
    const float* __restrict__ feats,   // [V][C][HW]
    const float* __restrict__ dvals,   // [D][HW]
    const float* __restrict__ wreg,    // [C]
    const float* __restrict__ mats,    // [2][12]
    float* __restrict__ cost)          // [D][HW]
{
    const int d0 = blockIdx.y * DG;
    const unsigned n = blockIdx.x * 256u + threadIdx.x;
    const int y = (int)(n / NW);
    const int x = (int)(n - (unsigned)y * NW);
    const float fx = (float)x, fy = (float)y;
    const unsigned voff = n * 4u;

    // per-view rot*(x,y,1) and translation (uniform mats -> scalar loads)
    float rxv[2], ryv[2], rzv[2], t0v[2], t1v[2], t2v[2];
#pragma unroll
    for (int v = 0; v < 2; ++v) {
        const float* m = mats + v * 12;
        rxv[v] = fmaf(m[0], fx, fmaf(m[1], fy, m[2]));
        ryv[v] = fmaf(m[3], fx, fmaf(m[4], fy, m[5]));
        rzv[v] = fmaf(m[6], fx, fmaf(m[7], fy, m[8]));
        t0v[v] = m[9]; t1v[v] = m[10]; t2v[v] = m[11];
    }

    // ---- reference window from the group's first depth (unconditional) ----
    const float dep0 = *(const float*)((const char*)dvals +
                                       (size_t)d0 * HW * 4 + voff);
    int x0r[2], y0r[2];
    unsigned co[2][4];
#pragma unroll
    for (int v = 0; v < 2; ++v) {
        float pxn = fmaf(rxv[v], dep0, t0v[v]);
        float pyn = fmaf(ryv[v], dep0, t1v[v]);
        float z   = fmaf(rzv[v], dep0, t2v[v]);
        z = (fabsf(z) < 1e-6f) ? 1e-6f : z;
        float px = pxn / z, py = pyn / z;   // IEEE div
        int x0 = (int)floorf(px), y0 = (int)floorf(py);
        x0r[v] = x0; y0r[v] = y0;
        int cx0 = min(max(x0, 0), NW - 1);
        int cx1 = min(max(x0 + 1, 0), NW - 1);
        int cy0 = min(max(y0, 0), NH - 1);
        int cy1 = min(max(y0 + 1, 0), NH - 1);
        co[v][0] = (unsigned)(cy0 * NW + cx0) * 4u;
        co[v][1] = (unsigned)(cy0 * NW + cx1) * 4u;
        co[v][2] = (unsigned)(cy1 * NW + cx0) * 4u;
        co[v][3] = (unsigned)(cy1 * NW + cx1) * 4u;
    }

    // ---- stream channels once into quadratic-form accumulators ----
    float G1[10], G2[10], Cm[16], R1[4], R2[4];
    float r2 = 0.f;
#pragma unroll
    for (int k = 0; k < 10; ++k) { G1[k] = 0.f; G2[k] = 0.f; }
#pragma unroll
    for (int k = 0; k < 16; ++k) Cm[k] = 0.f;
#pragma unroll
    for (int k = 0; k < 4; ++k) { R1[k] = 0.f; R2[k] = 0.f; }

    const char* f1b = (const char*)(feats + (size_t)1 * NC * HW);
    const char* f2b = (const char*)(feats + (size_t)2 * NC * HW);
#pragma unroll
    for (int c = 0; c < NC; ++c) {
        const char* frc = (const char*)feats + (size_t)c * HW * 4;
        const char* f1c = f1b + (size_t)c * HW * 4;
        const char* f2c = f2b + (size_t)c * HW * 4;
        float r = *(const float*)(frc + voff);
        float g1[4], g2[4];
#pragma unroll
        for (int i = 0; i < 4; ++i) {
            g1[i] = *(const float*)(f1c + co[0][i]);
            g2[i] = *(const float*)(f2c + co[1][i]);
        }
        float w = wreg[c];
        float wr = w * r;
        r2 = fmaf(wr, r, r2);
        float wg1[4], wg2[4];
#pragma unroll
        for (int i = 0; i < 4; ++i) { wg1[i] = w * g1[i]; wg2[i] = w * g2[i]; }
#pragma unroll
        for (int i = 0; i < 4; ++i) {
            R1[i] = fmaf(wr, g1[i], R1[i]);
            R2[i] = fmaf(wr, g2[i], R2[i]);
        }
#pragma unroll
        for (int i = 0; i < 4; ++i)
#pragma unroll
            for (int j = i; j < 4; ++j) {
                G1[SYM(i, j)] = fmaf(wg1[i], g1[j], G1[SYM(i, j)]);
                G2[SYM(i, j)] = fmaf(wg2[i], g2[j], G2[SYM(i, j)]);
            }
#pragma unroll
        for (int i = 0; i < 4; ++i)
#pragma unroll
            for (int j = 0; j < 4; ++j)
                Cm[i * 4 + j] = fmaf(wg1[i], g2[j], Cm[i * 4 + j]);
    }
    // fold the x2 of symmetric off-diagonals into G
#pragma unroll
    for (int i = 0; i < 4; ++i)
#pragma unroll
        for (int j = i + 1; j < 4; ++j) {
            G1[SYM(i, j)] += G1[SYM(i, j)];
            G2[SYM(i, j)] += G2[SYM(i, j)];
        }

    // ---- depth loop: weights only; zero loads on the fast path ----
    for (int dd = 0; dd < DG; ++dd) {
        const float depth = *(const float*)((const char*)dvals +
                             (size_t)(d0 + dd) * HW * 4 + voff);
        float al[2][4];
        int ax0[2], ay0[2];
        bool fast = true;
#pragma unroll
        for (int v = 0; v < 2; ++v) {
            float pxn = fmaf(rxv[v], depth, t0v[v]);
            float pyn = fmaf(ryv[v], depth, t1v[v]);
            float z   = fmaf(rzv[v], depth, t2v[v]);
            z = (fabsf(z) < 1e-6f) ? 1e-6f : z;
            float px = pxn / z, py = pyn / z;   // IEEE div
            float x0f = floorf(px), y0f = floorf(py);
            float wx = px - x0f, wy = py - y0f;
            int x0 = (int)x0f, y0 = (int)y0f;
            ax0[v] = x0; ay0[v] = y0;
            fast = fast && (x0 == x0r[v]) && (y0 == y0r[v]);
            bool vx0 = (x0 >= 0) && (x0 < NW);
            bool vx1 = (x0 + 1 >= 0) && (x0 + 1 < NW);
            bool vy0 = (y0 >= 0) && (y0 < NH);
            bool vy1 = (y0 + 1 >= 0) && (y0 + 1 < NH);
            al[v][0] = (1.f - wx) * (1.f - wy) * ((vx0 && vy0) ? 1.f : 0.f);
            al[v][1] = wx * (1.f - wy) * ((vx1 && vy0) ? 1.f : 0.f);
            al[v][2] = (1.f - wx) * wy * ((vx0 && vy1) ? 1.f : 0.f);
            al[v][3] = wx * wy * ((vx1 && vy1) ? 1.f : 0.f);
        }

        float cst;
        if (fast) {
            float q1 = 0.f, q2 = 0.f;
#pragma unroll
            for (int i = 0; i < 4; ++i)
#pragma unroll
                for (int j = i; j < 4; ++j) {
                    q1 = fmaf(G1[SYM(i, j)], al[0][i] * al[0][j], q1);
                    q2 = fmaf(G2[SYM(i, j)], al[1][i] * al[1][j], q2);
                }
            float qc = 0.f;
#pragma unroll
            for (int i = 0; i < 4; ++i)
#pragma unroll
                for (int j = 0; j < 4; ++j)
                    qc = fmaf(Cm[i * 4 + j], al[0][i] * al[1][j], qc);
            float lr = 0.f;
#pragma unroll
            for (int i = 0; i < 4; ++i) {
                lr = fmaf(R1[i], al[0][i], lr);
                lr = fmaf(R2[i], al[1][i], lr);
            }
            cst = (2.f / 9.f) * (r2 + q1 + q2 - lr - qc);
        } else {
            // slow path: exact direct recompute for deviant lanes only
            unsigned so[2][4];
#pragma unroll
            for (int v = 0; v < 2; ++v) {
                int cx0 = min(max(ax0[v], 0), NW - 1);
                int cx1 = min(max(ax0[v] + 1, 0), NW - 1);
                int cy0 = min(max(ay0[v], 0), NH - 1);
                int cy1 = min(max(ay0[v] + 1, 0), NH - 1);
                so[v][0] = (unsigned)(cy0 * NW + cx0) * 4u;
                so[v][1] = (unsigned)(cy0 * NW + cx1) * 4u;
                so[v][2] = (unsigned)(cy1 * NW + cx0) * 4u;
                so[v][3] = (unsigned)(cy1 * NW + cx1) * 4u;
            }
            float acc = 0.f;
#pragma unroll
            for (int c = 0; c < NC; ++c) {
                const char* frc = (const char*)feats + (size_t)c * HW * 4;
                const char* f1c = f1b + (size_t)c * HW * 4;
                const char* f2c = f2b + (size_t)c * HW * 4;
                float r = *(const float*)(frc + voff);
                float s1 = 0.f, s2 = 0.f;
#pragma unroll
                for (int i = 0; i < 4; ++i) {
                    s1 = fmaf(*(const float*)(f1c + so[0][i]), al[0][i], s1);
                    s2 = fmaf(*(const float*)(f2c + so[1][i]), al[1][i], s2);
                }
                float e = r * r + s1 * s1 + s2 * s2
                        - r * s1 - r * s2 - s1 * s2;
                acc = fmaf(wreg[c], e, acc);
            }
            cst = (2.f / 9.f) * acc;
        }
        *(float*)((char*)cost + (size_t)(d0 + dd) * HW * 4 + voff) = cst;
    }
}

// ---------------------------------------------------------------------------
// Softmax over D + depth regression + confidence (reads cost from prob
// region of d_out, overwrites with prob).
// ---------------------------------------------------------------------------
__global__ __launch_bounds__(256) void softmax_kernel(
    const float* __restrict__ dvals,
    float* __restrict__ out)
{
    int n = blockIdx.x * blockDim.x + threadIdx.x;
    float* prob = out + 2 * HW;

    float c[ND];
    float mx = -INFINITY;
#pragma unroll
    for (int d = 0; d < ND; ++d) {
        c[d] = prob[d * HW + n];
        mx = fmaxf(mx, c[d]);
    }
    float ssum = 0.f;
#pragma unroll
    for (int d = 0; d < ND; ++d) {
        float e = expf(c[d] - mx);
        c[d] = e;
        ssum += e;
    }
    float inv = 1.f / ssum;
    float depth_acc = 0.f, didx_acc = 0.f;
#pragma unroll
    for (int d = 0; d < ND; ++d) {
        float pv = c[d] * inv;
        c[d] = pv;
        prob[d * HW + n] = pv;
        depth_acc += pv * dvals[d * HW + n];
        didx_acc += pv * (float)d;
    }
    int di = (int)didx_acc;            // trunc toward zero, matches astype(int32)
    di = min(max(di, 0), ND - 1);
    float pdi = 0.f, pdi1 = 0.f;
#pragma unroll
    for (int d = 0; d < ND; ++d) {
        pdi = (d == di) ? c[d] : pdi;
        pdi1 = (d == di + 1) ? c[d] : pdi1;
    }
    out[n] = depth_acc;
    out[HW + n] = pdi + pdi1;
}

extern "C" void kernel_launch(void* const* d_in, const int* in_sizes, int n_in,
                              void* d_out, int out_size, void* d_ws, size_t ws_size,
                              hipStream_t stream) {
    const float* feats = (const float*)d_in[0];
    const float* pm    = (const float*)d_in[1];
    const float* dvals = (const float*)d_in[2];
    const float* wreg  = (const float*)d_in[3];
    float* out = (float*)d_out;
    float* mats = (float*)d_ws;                  // 24 floats

    proj_setup_kernel<<<1, 64, 0, stream>>>(pm, mats);
    cost_kernel8<<<dim3(HW / 256, ND / DG), 256, 0, stream>>>(
        feats, dvals, wreg, mats, out + 2 * HW);
    softmax_kernel<<<HW / 256, 256, 0, stream>>>(dvals, out);
}

// Round 9
// 56.128 us; speedup vs baseline: 25.5530x; 1.2032x over previous
//
#include <hip/hip_runtime.h>
#include <math.h>

namespace {
constexpr int NV = 3;    // views
constexpr int NC = 16;   // channels
constexpr int ND = 32;   // depths
constexpr int NH = 256;
constexpr int NW = 320;
constexpr int HW = NH * NW;       // 81920
constexpr int DG = 16;            // depths per thread
constexpr int CH = 8;             // depth chunk (batched divs)
#define SYM(i, j) ((i) * 4 + (j) - (i) * ((i) + 1) / 2)
}

// ---------------------------------------------------------------------------
// Setup: proj_v = P_v @ inv(P_0); store rot(9)+trans(3) per src view.
// ---------------------------------------------------------------------------
__global__ void proj_setup_kernel(const float* __restrict__ pm,
                                  float* __restrict__ mats) {
    if (threadIdx.x != 0 || blockIdx.x != 0) return;
    float P[NV][4][4];
    for (int v = 0; v < NV; ++v) {
        const float* E = pm + v * 2 * 16;
        const float* K = pm + v * 2 * 16 + 16;
        for (int i = 0; i < 4; ++i)
            for (int j = 0; j < 4; ++j)
                P[v][i][j] = E[i * 4 + j];
        for (int i = 0; i < 3; ++i)
            for (int j = 0; j < 4; ++j) {
                float acc = 0.f;
                for (int k = 0; k < 3; ++k) acc += K[i * 4 + k] * E[k * 4 + j];
                P[v][i][j] = acc;
            }
    }
    float A[4][8];
    for (int i = 0; i < 4; ++i)
        for (int j = 0; j < 4; ++j) {
            A[i][j] = P[0][i][j];
            A[i][j + 4] = (i == j) ? 1.f : 0.f;
        }
    for (int col = 0; col < 4; ++col) {
        int piv = col;
        float best = fabsf(A[col][col]);
        for (int r = col + 1; r < 4; ++r) {
            float av = fabsf(A[r][col]);
            if (av > best) { best = av; piv = r; }
        }
        if (piv != col)
            for (int j = 0; j < 8; ++j) {
                float t = A[col][j]; A[col][j] = A[piv][j]; A[piv][j] = t;
            }
        float inv = 1.f / A[col][col];
        for (int j = 0; j < 8; ++j) A[col][j] *= inv;
        for (int r = 0; r < 4; ++r) {
            if (r == col) continue;
            float f = A[r][col];
            if (f != 0.f)
                for (int j = 0; j < 8; ++j) A[r][j] -= f * A[col][j];
        }
    }
    float Inv[4][4];
    for (int i = 0; i < 4; ++i)
        for (int j = 0; j < 4; ++j) Inv[i][j] = A[i][j + 4];

    for (int v = 1; v < NV; ++v) {
        float M[4][4];
        for (int i = 0; i < 4; ++i)
            for (int j = 0; j < 4; ++j) {
                float acc = 0.f;
                for (int k = 0; k < 4; ++k) acc += P[v][i][k] * Inv[k][j];
                M[i][j] = acc;
            }
        float* o = mats + (v - 1) * 12;
        for (int i = 0; i < 3; ++i)
            for (int j = 0; j < 3; ++j) o[i * 3 + j] = M[i][j];
        for (int i = 0; i < 3; ++i) o[9 + i] = M[i][3];
    }
}

// ---------------------------------------------------------------------------
// Cost volume R9 = R8 quad-form + two latency fixes:
//  (1) DG=16 (2 threads/pixel): stats stream amortized over 16 depths and
//      640 blocks restore ~10-12 waves/CU (R8: 1280 blocks but VGPR-capped
//      at 3 waves/SIMD with a serial depth loop -> latency-bound).
//  (2) depths processed in chunks of 8 with ALL 16 IEEE divs of the chunk
//      batched into unrolled, independent chains before the weight/eval
//      unroll -> divisions pipeline instead of serializing.
// Quadratic form: cost(d) = (2/9)[r2 + a'G1a + b'G2b - R1.a - R2.b - a'Cb],
// only the bilinear weights (a,b) depend on depth. Slow path (per-lane exact
// regather) guards arbitrary inputs; execz-skipped when windows match d0's.
// All register arrays statically indexed (R7 lesson: conditional loop-carried
// arrays -> scratch).
// ---------------------------------------------------------------------------
__global__ __launch_bounds__(256) void cost_kernel9(
    const float* __restrict__ feats,   // [V][C][HW]
    const float* __restrict__ dvals,   // [D][HW]
    const float* __restrict__ wreg,    // [C]
    const float* __restrict__ mats,    // [2][12]
    float* __restrict__ cost)          // [D][HW]
{
    const int d0 = blockIdx.y * DG;
    const unsigned n = blockIdx.x * 256u + threadIdx.x;
    const int y = (int)(n / NW);
    const int x = (int)(n - (unsigned)y * NW);
    const float fx = (float)x, fy = (float)y;
    const unsigned voff = n * 4u;

    float rxv[2], ryv[2], rzv[2], t0v[2], t1v[2], t2v[2];
#pragma unroll
    for (int v = 0; v < 2; ++v) {
        const float* m = mats + v * 12;
        rxv[v] = fmaf(m[0], fx, fmaf(m[1], fy, m[2]));
        ryv[v] = fmaf(m[3], fx, fmaf(m[4], fy, m[5]));
        rzv[v] = fmaf(m[6], fx, fmaf(m[7], fy, m[8]));
        t0v[v] = m[9]; t1v[v] = m[10]; t2v[v] = m[11];
    }

    // ---- reference window from the group's first depth (unconditional) ----
    const float dep0 = *(const float*)((const char*)dvals +
                                       (size_t)d0 * HW * 4 + voff);
    int x0r[2], y0r[2];
    unsigned co[2][4];
#pragma unroll
    for (int v = 0; v < 2; ++v) {
        float pxn = fmaf(rxv[v], dep0, t0v[v]);
        float pyn = fmaf(ryv[v], dep0, t1v[v]);
        float z   = fmaf(rzv[v], dep0, t2v[v]);
        z = (fabsf(z) < 1e-6f) ? 1e-6f : z;
        float px = pxn / z, py = pyn / z;
        int x0 = (int)floorf(px), y0 = (int)floorf(py);
        x0r[v] = x0; y0r[v] = y0;
        int cx0 = min(max(x0, 0), NW - 1);
        int cx1 = min(max(x0 + 1, 0), NW - 1);
        int cy0 = min(max(y0, 0), NH - 1);
        int cy1 = min(max(y0 + 1, 0), NH - 1);
        co[v][0] = (unsigned)(cy0 * NW + cx0) * 4u;
        co[v][1] = (unsigned)(cy0 * NW + cx1) * 4u;
        co[v][2] = (unsigned)(cy1 * NW + cx0) * 4u;
        co[v][3] = (unsigned)(cy1 * NW + cx1) * 4u;
    }

    // ---- stream channels once into quadratic-form accumulators ----
    float G1[10], G2[10], Cm[16], R1[4], R2[4];
    float r2 = 0.f;
#pragma unroll
    for (int k = 0; k < 10; ++k) { G1[k] = 0.f; G2[k] = 0.f; }
#pragma unroll
    for (int k = 0; k < 16; ++k) Cm[k] = 0.f;
#pragma unroll
    for (int k = 0; k < 4; ++k) { R1[k] = 0.f; R2[k] = 0.f; }

    const char* f1b = (const char*)(feats + (size_t)1 * NC * HW);
    const char* f2b = (const char*)(feats + (size_t)2 * NC * HW);
#pragma unroll
    for (int c = 0; c < NC; ++c) {
        const char* frc = (const char*)feats + (size_t)c * HW * 4;
        const char* f1c = f1b + (size_t)c * HW * 4;
        const char* f2c = f2b + (size_t)c * HW * 4;
        float r = *(const float*)(frc + voff);
        float g1[4], g2[4];
#pragma unroll
        for (int i = 0; i < 4; ++i) {
            g1[i] = *(const float*)(f1c + co[0][i]);
            g2[i] = *(const float*)(f2c + co[1][i]);
        }
        float w = wreg[c];
        float wr = w * r;
        r2 = fmaf(wr, r, r2);
        float wg1[4], wg2[4];
#pragma unroll
        for (int i = 0; i < 4; ++i) { wg1[i] = w * g1[i]; wg2[i] = w * g2[i]; }
#pragma unroll
        for (int i = 0; i < 4; ++i) {
            R1[i] = fmaf(wr, g1[i], R1[i]);
            R2[i] = fmaf(wr, g2[i], R2[i]);
        }
#pragma unroll
        for (int i = 0; i < 4; ++i)
#pragma unroll
            for (int j = i; j < 4; ++j) {
                G1[SYM(i, j)] = fmaf(wg1[i], g1[j], G1[SYM(i, j)]);
                G2[SYM(i, j)] = fmaf(wg2[i], g2[j], G2[SYM(i, j)]);
            }
#pragma unroll
        for (int i = 0; i < 4; ++i)
#pragma unroll
            for (int j = 0; j < 4; ++j)
                Cm[i * 4 + j] = fmaf(wg1[i], g2[j], Cm[i * 4 + j]);
    }
#pragma unroll
    for (int i = 0; i < 4; ++i)
#pragma unroll
        for (int j = i + 1; j < 4; ++j) {
            G1[SYM(i, j)] += G1[SYM(i, j)];
            G2[SYM(i, j)] += G2[SYM(i, j)];
        }

    // ---- depth loop: chunks of 8, divs batched, weights-only fast path ----
#pragma unroll
    for (int ck = 0; ck < DG / CH; ++ck) {
        float pxs[2][CH], pys[2][CH];
        // batched projection: 16 independent div chains pipeline
#pragma unroll
        for (int dd = 0; dd < CH; ++dd) {
            const float depth = *(const float*)((const char*)dvals +
                                 (size_t)(d0 + ck * CH + dd) * HW * 4 + voff);
#pragma unroll
            for (int v = 0; v < 2; ++v) {
                float pxn = fmaf(rxv[v], depth, t0v[v]);
                float pyn = fmaf(ryv[v], depth, t1v[v]);
                float z   = fmaf(rzv[v], depth, t2v[v]);
                z = (fabsf(z) < 1e-6f) ? 1e-6f : z;
                pxs[v][dd] = pxn / z;
                pys[v][dd] = pyn / z;
            }
        }
#pragma unroll
        for (int dd = 0; dd < CH; ++dd) {
            float al[2][4];
            int ax0[2], ay0[2];
            bool fast = true;
#pragma unroll
            for (int v = 0; v < 2; ++v) {
                float px = pxs[v][dd], py = pys[v][dd];
                float x0f = floorf(px), y0f = floorf(py);
                float wx = px - x0f, wy = py - y0f;
                int x0 = (int)x0f, y0 = (int)y0f;
                ax0[v] = x0; ay0[v] = y0;
                fast = fast && (x0 == x0r[v]) && (y0 == y0r[v]);
                bool vx0 = (x0 >= 0) && (x0 < NW);
                bool vx1 = (x0 + 1 >= 0) && (x0 + 1 < NW);
                bool vy0 = (y0 >= 0) && (y0 < NH);
                bool vy1 = (y0 + 1 >= 0) && (y0 + 1 < NH);
                al[v][0] = (1.f - wx) * (1.f - wy) * ((vx0 && vy0) ? 1.f : 0.f);
                al[v][1] = wx * (1.f - wy) * ((vx1 && vy0) ? 1.f : 0.f);
                al[v][2] = (1.f - wx) * wy * ((vx0 && vy1) ? 1.f : 0.f);
                al[v][3] = wx * wy * ((vx1 && vy1) ? 1.f : 0.f);
            }

            float cst;
            if (fast) {
                float q1 = 0.f, q2 = 0.f;
#pragma unroll
                for (int i = 0; i < 4; ++i)
#pragma unroll
                    for (int j = i; j < 4; ++j) {
                        q1 = fmaf(G1[SYM(i, j)], al[0][i] * al[0][j], q1);
                        q2 = fmaf(G2[SYM(i, j)], al[1][i] * al[1][j], q2);
                    }
                float qc = 0.f;
#pragma unroll
                for (int i = 0; i < 4; ++i)
#pragma unroll
                    for (int j = 0; j < 4; ++j)
                        qc = fmaf(Cm[i * 4 + j], al[0][i] * al[1][j], qc);
                float lr = 0.f;
#pragma unroll
                for (int i = 0; i < 4; ++i) {
                    lr = fmaf(R1[i], al[0][i], lr);
                    lr = fmaf(R2[i], al[1][i], lr);
                }
                cst = (2.f / 9.f) * (r2 + q1 + q2 - lr - qc);
            } else {
                // slow path: exact direct regather for deviant lanes only
                unsigned so[2][4];
#pragma unroll
                for (int v = 0; v < 2; ++v) {
                    int cx0 = min(max(ax0[v], 0), NW - 1);
                    int cx1 = min(max(ax0[v] + 1, 0), NW - 1);
                    int cy0 = min(max(ay0[v], 0), NH - 1);
                    int cy1 = min(max(ay0[v] + 1, 0), NH - 1);
                    so[v][0] = (unsigned)(cy0 * NW + cx0) * 4u;
                    so[v][1] = (unsigned)(cy0 * NW + cx1) * 4u;
                    so[v][2] = (unsigned)(cy1 * NW + cx0) * 4u;
                    so[v][3] = (unsigned)(cy1 * NW + cx1) * 4u;
                }
                float acc = 0.f;
#pragma unroll
                for (int c = 0; c < NC; ++c) {
                    const char* frc = (const char*)feats + (size_t)c * HW * 4;
                    const char* f1c = f1b + (size_t)c * HW * 4;
                    const char* f2c = f2b + (size_t)c * HW * 4;
                    float r = *(const float*)(frc + voff);
                    float s1 = 0.f, s2 = 0.f;
#pragma unroll
                    for (int i = 0; i < 4; ++i) {
                        s1 = fmaf(*(const float*)(f1c + so[0][i]), al[0][i], s1);
                        s2 = fmaf(*(const float*)(f2c + so[1][i]), al[1][i], s2);
                    }
                    float e = r * r + s1 * s1 + s2 * s2
                            - r * s1 - r * s2 - s1 * s2;
                    acc = fmaf(wreg[c], e, acc);
                }
                cst = (2.f / 9.f) * acc;
            }
            *(float*)((char*)cost +
                      (size_t)(d0 + ck * CH + dd) * HW * 4 + voff) = cst;
        }
    }
}

// ---------------------------------------------------------------------------
// Softmax over D + depth regression + confidence.
// ---------------------------------------------------------------------------
__global__ __launch_bounds__(256) void softmax_kernel(
    const float* __restrict__ dvals,
    float* __restrict__ out)
{
    int n = blockIdx.x * blockDim.x + threadIdx.x;
    float* prob = out + 2 * HW;

    float c[ND];
    float mx = -INFINITY;
#pragma unroll
    for (int d = 0; d < ND; ++d) {
        c[d] = prob[d * HW + n];
        mx = fmaxf(mx, c[d]);
    }
    float ssum = 0.f;
#pragma unroll
    for (int d = 0; d < ND; ++d) {
        float e = expf(c[d] - mx);
        c[d] = e;
        ssum += e;
    }
    float inv = 1.f / ssum;
    float depth_acc = 0.f, didx_acc = 0.f;
#pragma unroll
    for (int d = 0; d < ND; ++d) {
        float pv = c[d] * inv;
        c[d] = pv;
        prob[d * HW + n] = pv;
        depth_acc += pv * dvals[d * HW + n];
        didx_acc += pv * (float)d;
    }
    int di = (int)didx_acc;
    di = min(max(di, 0), ND - 1);
    float pdi = 0.f, pdi1 = 0.f;
#pragma unroll
    for (int d = 0; d < ND; ++d) {
        pdi = (d == di) ? c[d] : pdi;
        pdi1 = (d == di + 1) ? c[d] : pdi1;
    }
    out[n] = depth_acc;
    out[HW + n] = pdi + pdi1;
}

extern "C" void kernel_launch(void* const* d_in, const int* in_sizes, int n_in,
                              void* d_out, int out_size, void* d_ws, size_t ws_size,
                              hipStream_t stream) {
    const float* feats = (const float*)d_in[0];
    const float* pm    = (const float*)d_in[1];
    const float* dvals = (const float*)d_in[2];
    const float* wreg  = (const float*)d_in[3];
    float* out = (float*)d_out;
    float* mats = (float*)d_ws;                  // 24 floats

    proj_setup_kernel<<<1, 64, 0, stream>>>(pm, mats);
    cost_kernel9<<<dim3(HW / 256, ND / DG), 256, 0, stream>>>(
        feats, dvals, wreg, mats, out + 2 * HW);
    softmax_kernel<<<HW / 256, 256, 0, stream>>>(dvals, out);
}

// Round 10
// 43.874 us; speedup vs baseline: 32.6901x; 1.2793x over previous
//
#include <hip/hip_runtime.h>
#include <math.h>

namespace {
constexpr int NV = 3;    // views
constexpr int NC = 16;   // channels
constexpr int ND = 32;   // depths
constexpr int NH = 256;
constexpr int NW = 320;
constexpr int HW = NH * NW;       // 81920
constexpr int DG = 16;            // depths/thread (fused fallback)
constexpr int CHF = 8;            // div chunk (fused fallback)
constexpr int DGE = 8;            // depths/thread (eval kernel)
constexpr size_t COEF_OFF = 128;
constexpr size_t COEF_BYTES = (size_t)45 * HW * sizeof(float);  // 14.7 MB
#define SYM(i, j) ((i) * 4 + (j) - (i) * ((i) + 1) / 2)
}

// ---------------------------------------------------------------------------
// Setup: proj_v = P_v @ inv(P_0); store rot(9)+trans(3) per src view.
// ---------------------------------------------------------------------------
__global__ void proj_setup_kernel(const float* __restrict__ pm,
                                  float* __restrict__ mats) {
    if (threadIdx.x != 0 || blockIdx.x != 0) return;
    float P[NV][4][4];
    for (int v = 0; v < NV; ++v) {
        const float* E = pm + v * 2 * 16;
        const float* K = pm + v * 2 * 16 + 16;
        for (int i = 0; i < 4; ++i)
            for (int j = 0; j < 4; ++j)
                P[v][i][j] = E[i * 4 + j];
        for (int i = 0; i < 3; ++i)
            for (int j = 0; j < 4; ++j) {
                float acc = 0.f;
                for (int k = 0; k < 3; ++k) acc += K[i * 4 + k] * E[k * 4 + j];
                P[v][i][j] = acc;
            }
    }
    float A[4][8];
    for (int i = 0; i < 4; ++i)
        for (int j = 0; j < 4; ++j) {
            A[i][j] = P[0][i][j];
            A[i][j + 4] = (i == j) ? 1.f : 0.f;
        }
    for (int col = 0; col < 4; ++col) {
        int piv = col;
        float best = fabsf(A[col][col]);
        for (int r = col + 1; r < 4; ++r) {
            float av = fabsf(A[r][col]);
            if (av > best) { best = av; piv = r; }
        }
        if (piv != col)
            for (int j = 0; j < 8; ++j) {
                float t = A[col][j]; A[col][j] = A[piv][j]; A[piv][j] = t;
            }
        float inv = 1.f / A[col][col];
        for (int j = 0; j < 8; ++j) A[col][j] *= inv;
        for (int r = 0; r < 4; ++r) {
            if (r == col) continue;
            float f = A[r][col];
            if (f != 0.f)
                for (int j = 0; j < 8; ++j) A[r][j] -= f * A[col][j];
        }
    }
    float Inv[4][4];
    for (int i = 0; i < 4; ++i)
        for (int j = 0; j < 4; ++j) Inv[i][j] = A[i][j + 4];

    for (int v = 1; v < NV; ++v) {
        float M[4][4];
        for (int i = 0; i < 4; ++i)
            for (int j = 0; j < 4; ++j) {
                float acc = 0.f;
                for (int k = 0; k < 4; ++k) acc += P[v][i][k] * Inv[k][j];
                M[i][j] = acc;
            }
        float* o = mats + (v - 1) * 12;
        for (int i = 0; i < 3; ++i)
            for (int j = 0; j < 3; ++j) o[i * 3 + j] = M[i][j];
        for (int i = 0; i < 3; ++i) o[9 + i] = M[i][3];
    }
}

// ---------------------------------------------------------------------------
// Phase 1: per-pixel quad-form coefficients (depth-independent), SoA planes.
// Window anchored at depth plane 0. 45 planes: 0 r2 | 1-4 R1 | 5-8 R2 |
// 9-18 G1 | 19-28 G2 | 29-44 Cm. One thread/pixel; 64-thread blocks for CU
// spread (only 1280 waves total, so runtime ~ per-wave latency, which is
// 144 coherent batched loads + ~900 VALU).
// ---------------------------------------------------------------------------
__global__ __launch_bounds__(64) void stats_kernel(
    const float* __restrict__ feats,   // [V][C][HW]
    const float* __restrict__ dvals,   // [D][HW]
    const float* __restrict__ wreg,    // [C]
    const float* __restrict__ mats,    // [2][12]
    float* __restrict__ coef)          // [45][HW]
{
    const unsigned n = blockIdx.x * 64u + threadIdx.x;
    const int y = (int)(n / NW);
    const int x = (int)(n - (unsigned)y * NW);
    const float fx = (float)x, fy = (float)y;
    const unsigned voff = n * 4u;

    float rxv[2], ryv[2], rzv[2], t0v[2], t1v[2], t2v[2];
#pragma unroll
    for (int v = 0; v < 2; ++v) {
        const float* m = mats + v * 12;
        rxv[v] = fmaf(m[0], fx, fmaf(m[1], fy, m[2]));
        ryv[v] = fmaf(m[3], fx, fmaf(m[4], fy, m[5]));
        rzv[v] = fmaf(m[6], fx, fmaf(m[7], fy, m[8]));
        t0v[v] = m[9]; t1v[v] = m[10]; t2v[v] = m[11];
    }

    const float dep0 = *(const float*)((const char*)dvals + voff); // plane 0
    unsigned co[2][4];
#pragma unroll
    for (int v = 0; v < 2; ++v) {
        float pxn = fmaf(rxv[v], dep0, t0v[v]);
        float pyn = fmaf(ryv[v], dep0, t1v[v]);
        float z   = fmaf(rzv[v], dep0, t2v[v]);
        z = (fabsf(z) < 1e-6f) ? 1e-6f : z;
        float px = pxn / z, py = pyn / z;    // IEEE div (matches eval)
        int x0 = (int)floorf(px), y0 = (int)floorf(py);
        int cx0 = min(max(x0, 0), NW - 1);
        int cx1 = min(max(x0 + 1, 0), NW - 1);
        int cy0 = min(max(y0, 0), NH - 1);
        int cy1 = min(max(y0 + 1, 0), NH - 1);
        co[v][0] = (unsigned)(cy0 * NW + cx0) * 4u;
        co[v][1] = (unsigned)(cy0 * NW + cx1) * 4u;
        co[v][2] = (unsigned)(cy1 * NW + cx0) * 4u;
        co[v][3] = (unsigned)(cy1 * NW + cx1) * 4u;
    }

    float G1[10], G2[10], Cm[16], R1[4], R2[4];
    float r2 = 0.f;
#pragma unroll
    for (int k = 0; k < 10; ++k) { G1[k] = 0.f; G2[k] = 0.f; }
#pragma unroll
    for (int k = 0; k < 16; ++k) Cm[k] = 0.f;
#pragma unroll
    for (int k = 0; k < 4; ++k) { R1[k] = 0.f; R2[k] = 0.f; }

    const char* f1b = (const char*)(feats + (size_t)1 * NC * HW);
    const char* f2b = (const char*)(feats + (size_t)2 * NC * HW);
#pragma unroll
    for (int c = 0; c < NC; ++c) {
        const char* frc = (const char*)feats + (size_t)c * HW * 4;
        const char* f1c = f1b + (size_t)c * HW * 4;
        const char* f2c = f2b + (size_t)c * HW * 4;
        float r = *(const float*)(frc + voff);
        float g1[4], g2[4];
#pragma unroll
        for (int i = 0; i < 4; ++i) {
            g1[i] = *(const float*)(f1c + co[0][i]);
            g2[i] = *(const float*)(f2c + co[1][i]);
        }
        float w = wreg[c];
        float wr = w * r;
        r2 = fmaf(wr, r, r2);
        float wg1[4], wg2[4];
#pragma unroll
        for (int i = 0; i < 4; ++i) { wg1[i] = w * g1[i]; wg2[i] = w * g2[i]; }
#pragma unroll
        for (int i = 0; i < 4; ++i) {
            R1[i] = fmaf(wr, g1[i], R1[i]);
            R2[i] = fmaf(wr, g2[i], R2[i]);
        }
#pragma unroll
        for (int i = 0; i < 4; ++i)
#pragma unroll
            for (int j = i; j < 4; ++j) {
                G1[SYM(i, j)] = fmaf(wg1[i], g1[j], G1[SYM(i, j)]);
                G2[SYM(i, j)] = fmaf(wg2[i], g2[j], G2[SYM(i, j)]);
            }
#pragma unroll
        for (int i = 0; i < 4; ++i)
#pragma unroll
            for (int j = 0; j < 4; ++j)
                Cm[i * 4 + j] = fmaf(wg1[i], g2[j], Cm[i * 4 + j]);
    }
#pragma unroll
    for (int i = 0; i < 4; ++i)
#pragma unroll
        for (int j = i + 1; j < 4; ++j) {
            G1[SYM(i, j)] += G1[SYM(i, j)];
            G2[SYM(i, j)] += G2[SYM(i, j)];
        }

    char* cb = (char*)coef;
    *(float*)(cb + (size_t)0 * HW * 4 + voff) = r2;
#pragma unroll
    for (int i = 0; i < 4; ++i) {
        *(float*)(cb + (size_t)(1 + i) * HW * 4 + voff) = R1[i];
        *(float*)(cb + (size_t)(5 + i) * HW * 4 + voff) = R2[i];
    }
#pragma unroll
    for (int k = 0; k < 10; ++k) {
        *(float*)(cb + (size_t)(9 + k) * HW * 4 + voff) = G1[k];
        *(float*)(cb + (size_t)(19 + k) * HW * 4 + voff) = G2[k];
    }
#pragma unroll
    for (int k = 0; k < 16; ++k)
        *(float*)(cb + (size_t)(29 + k) * HW * 4 + voff) = Cm[k];
}

// ---------------------------------------------------------------------------
// Phase 2: evaluate 8 depths per thread from the 45 coefficients. Divs
// batched 4-wide. Fast path identical numerics to the R9 fused kernel;
// per-lane slow path (direct regather) guards generic inputs, anchored at
// the same depth-plane-0 window as stats_kernel.
// ---------------------------------------------------------------------------
__global__ __launch_bounds__(256) void eval_kernel(
    const float* __restrict__ feats,
    const float* __restrict__ dvals,
    const float* __restrict__ wreg,
    const float* __restrict__ mats,
    const float* __restrict__ coef,    // [45][HW]
    float* __restrict__ cost)          // [D][HW]
{
    const int d0 = blockIdx.y * DGE;
    const unsigned n = blockIdx.x * 256u + threadIdx.x;
    const int y = (int)(n / NW);
    const int x = (int)(n - (unsigned)y * NW);
    const float fx = (float)x, fy = (float)y;
    const unsigned voff = n * 4u;

    float rxv[2], ryv[2], rzv[2], t0v[2], t1v[2], t2v[2];
#pragma unroll
    for (int v = 0; v < 2; ++v) {
        const float* m = mats + v * 12;
        rxv[v] = fmaf(m[0], fx, fmaf(m[1], fy, m[2]));
        ryv[v] = fmaf(m[3], fx, fmaf(m[4], fy, m[5]));
        rzv[v] = fmaf(m[6], fx, fmaf(m[7], fy, m[8]));
        t0v[v] = m[9]; t1v[v] = m[10]; t2v[v] = m[11];
    }

    // reference window from depth plane 0 (same expressions as stats_kernel)
    const float dep0 = *(const float*)((const char*)dvals + voff);
    int x0r[2], y0r[2];
#pragma unroll
    for (int v = 0; v < 2; ++v) {
        float pxn = fmaf(rxv[v], dep0, t0v[v]);
        float pyn = fmaf(ryv[v], dep0, t1v[v]);
        float z   = fmaf(rzv[v], dep0, t2v[v]);
        z = (fabsf(z) < 1e-6f) ? 1e-6f : z;
        float px = pxn / z, py = pyn / z;
        x0r[v] = (int)floorf(px);
        y0r[v] = (int)floorf(py);
    }

    // 45 coefficient loads, SGPR bases + shared voffset
    const char* cb = (const char*)coef;
    float r2 = *(const float*)(cb + (size_t)0 * HW * 4 + voff);
    float R1[4], R2[4], G1[10], G2[10], Cm[16];
#pragma unroll
    for (int i = 0; i < 4; ++i) {
        R1[i] = *(const float*)(cb + (size_t)(1 + i) * HW * 4 + voff);
        R2[i] = *(const float*)(cb + (size_t)(5 + i) * HW * 4 + voff);
    }
#pragma unroll
    for (int k = 0; k < 10; ++k) {
        G1[k] = *(const float*)(cb + (size_t)(9 + k) * HW * 4 + voff);
        G2[k] = *(const float*)(cb + (size_t)(19 + k) * HW * 4 + voff);
    }
#pragma unroll
    for (int k = 0; k < 16; ++k)
        Cm[k] = *(const float*)(cb + (size_t)(29 + k) * HW * 4 + voff);

    const char* f1b = (const char*)(feats + (size_t)1 * NC * HW);
    const char* f2b = (const char*)(feats + (size_t)2 * NC * HW);

#pragma unroll
    for (int ck = 0; ck < DGE / 4; ++ck) {
        float pxs[2][4], pys[2][4];
#pragma unroll
        for (int dd = 0; dd < 4; ++dd) {
            const float depth = *(const float*)((const char*)dvals +
                                 (size_t)(d0 + ck * 4 + dd) * HW * 4 + voff);
#pragma unroll
            for (int v = 0; v < 2; ++v) {
                float pxn = fmaf(rxv[v], depth, t0v[v]);
                float pyn = fmaf(ryv[v], depth, t1v[v]);
                float z   = fmaf(rzv[v], depth, t2v[v]);
                z = (fabsf(z) < 1e-6f) ? 1e-6f : z;
                pxs[v][dd] = pxn / z;
                pys[v][dd] = pyn / z;
            }
        }
#pragma unroll
        for (int dd = 0; dd < 4; ++dd) {
            float al[2][4];
            int ax0[2], ay0[2];
            bool fast = true;
#pragma unroll
            for (int v = 0; v < 2; ++v) {
                float px = pxs[v][dd], py = pys[v][dd];
                float x0f = floorf(px), y0f = floorf(py);
                float wx = px - x0f, wy = py - y0f;
                int x0 = (int)x0f, y0 = (int)y0f;
                ax0[v] = x0; ay0[v] = y0;
                fast = fast && (x0 == x0r[v]) && (y0 == y0r[v]);
                bool vx0 = (x0 >= 0) && (x0 < NW);
                bool vx1 = (x0 + 1 >= 0) && (x0 + 1 < NW);
                bool vy0 = (y0 >= 0) && (y0 < NH);
                bool vy1 = (y0 + 1 >= 0) && (y0 + 1 < NH);
                al[v][0] = (1.f - wx) * (1.f - wy) * ((vx0 && vy0) ? 1.f : 0.f);
                al[v][1] = wx * (1.f - wy) * ((vx1 && vy0) ? 1.f : 0.f);
                al[v][2] = (1.f - wx) * wy * ((vx0 && vy1) ? 1.f : 0.f);
                al[v][3] = wx * wy * ((vx1 && vy1) ? 1.f : 0.f);
            }

            float cst;
            if (fast) {
                float q1 = 0.f, q2 = 0.f;
#pragma unroll
                for (int i = 0; i < 4; ++i)
#pragma unroll
                    for (int j = i; j < 4; ++j) {
                        q1 = fmaf(G1[SYM(i, j)], al[0][i] * al[0][j], q1);
                        q2 = fmaf(G2[SYM(i, j)], al[1][i] * al[1][j], q2);
                    }
                float qc = 0.f;
#pragma unroll
                for (int i = 0; i < 4; ++i)
#pragma unroll
                    for (int j = 0; j < 4; ++j)
                        qc = fmaf(Cm[i * 4 + j], al[0][i] * al[1][j], qc);
                float lr = 0.f;
#pragma unroll
                for (int i = 0; i < 4; ++i) {
                    lr = fmaf(R1[i], al[0][i], lr);
                    lr = fmaf(R2[i], al[1][i], lr);
                }
                cst = (2.f / 9.f) * (r2 + q1 + q2 - lr - qc);
            } else {
                unsigned so[2][4];
#pragma unroll
                for (int v = 0; v < 2; ++v) {
                    int cx0 = min(max(ax0[v], 0), NW - 1);
                    int cx1 = min(max(ax0[v] + 1, 0), NW - 1);
                    int cy0 = min(max(ay0[v], 0), NH - 1);
                    int cy1 = min(max(ay0[v] + 1, 0), NH - 1);
                    so[v][0] = (unsigned)(cy0 * NW + cx0) * 4u;
                    so[v][1] = (unsigned)(cy0 * NW + cx1) * 4u;
                    so[v][2] = (unsigned)(cy1 * NW + cx0) * 4u;
                    so[v][3] = (unsigned)(cy1 * NW + cx1) * 4u;
                }
                float acc = 0.f;
#pragma unroll
                for (int c = 0; c < NC; ++c) {
                    const char* frc = (const char*)feats + (size_t)c * HW * 4;
                    const char* f1c = f1b + (size_t)c * HW * 4;
                    const char* f2c = f2b + (size_t)c * HW * 4;
                    float r = *(const float*)(frc + voff);
                    float s1 = 0.f, s2 = 0.f;
#pragma unroll
                    for (int i = 0; i < 4; ++i) {
                        s1 = fmaf(*(const float*)(f1c + so[0][i]), al[0][i], s1);
                        s2 = fmaf(*(const float*)(f2c + so[1][i]), al[1][i], s2);
                    }
                    float e = r * r + s1 * s1 + s2 * s2
                            - r * s1 - r * s2 - s1 * s2;
                    acc = fmaf(wreg[c], e, acc);
                }
                cst = (2.f / 9.f) * acc;
            }
            *(float*)((char*)cost +
                      (size_t)(d0 + ck * 4 + dd) * HW * 4 + voff) = cst;
        }
    }
}

// ---------------------------------------------------------------------------
// Fused fallback (R9 kernel, verbatim) for when ws can't hold the coeffs.
// ---------------------------------------------------------------------------
__global__ __launch_bounds__(256) void cost_kernel9(
    const float* __restrict__ feats,
    const float* __restrict__ dvals,
    const float* __restrict__ wreg,
    const float* __restrict__ mats,
    float* __restrict__ cost)
{
    const int d0 = blockIdx.y * DG;
    const unsigned n = blockIdx.x * 256u + threadIdx.x;
    const int y = (int)(n / NW);
    const int x = (int)(n - (unsigned)y * NW);
    const float fx = (float)x, fy = (float)y;
    const unsigned voff = n * 4u;

    float rxv[2], ryv[2], rzv[2], t0v[2], t1v[2], t2v[2];
#pragma unroll
    for (int v = 0; v < 2; ++v) {
        const float* m = mats + v * 12;
        rxv[v] = fmaf(m[0], fx, fmaf(m[1], fy, m[2]));
        ryv[v] = fmaf(m[3], fx, fmaf(m[4], fy, m[5]));
        rzv[v] = fmaf(m[6], fx, fmaf(m[7], fy, m[8]));
        t0v[v] = m[9]; t1v[v] = m[10]; t2v[v] = m[11];
    }

    const float dep0 = *(const float*)((const char*)dvals +
                                       (size_t)d0 * HW * 4 + voff);
    int x0r[2], y0r[2];
    unsigned co[2][4];
#pragma unroll
    for (int v = 0; v < 2; ++v) {
        float pxn = fmaf(rxv[v], dep0, t0v[v]);
        float pyn = fmaf(ryv[v], dep0, t1v[v]);
        float z   = fmaf(rzv[v], dep0, t2v[v]);
        z = (fabsf(z) < 1e-6f) ? 1e-6f : z;
        float px = pxn / z, py = pyn / z;
        int x0 = (int)floorf(px), y0 = (int)floorf(py);
        x0r[v] = x0; y0r[v] = y0;
        int cx0 = min(max(x0, 0), NW - 1);
        int cx1 = min(max(x0 + 1, 0), NW - 1);
        int cy0 = min(max(y0, 0), NH - 1);
        int cy1 = min(max(y0 + 1, 0), NH - 1);
        co[v][0] = (unsigned)(cy0 * NW + cx0) * 4u;
        co[v][1] = (unsigned)(cy0 * NW + cx1) * 4u;
        co[v][2] = (unsigned)(cy1 * NW + cx0) * 4u;
        co[v][3] = (unsigned)(cy1 * NW + cx1) * 4u;
    }

    float G1[10], G2[10], Cm[16], R1[4], R2[4];
    float r2 = 0.f;
#pragma unroll
    for (int k = 0; k < 10; ++k) { G1[k] = 0.f; G2[k] = 0.f; }
#pragma unroll
    for (int k = 0; k < 16; ++k) Cm[k] = 0.f;
#pragma unroll
    for (int k = 0; k < 4; ++k) { R1[k] = 0.f; R2[k] = 0.f; }

    const char* f1b = (const char*)(feats + (size_t)1 * NC * HW);
    const char* f2b = (const char*)(feats + (size_t)2 * NC * HW);
#pragma unroll
    for (int c = 0; c < NC; ++c) {
        const char* frc = (const char*)feats + (size_t)c * HW * 4;
        const char* f1c = f1b + (size_t)c * HW * 4;
        const char* f2c = f2b + (size_t)c * HW * 4;
        float r = *(const float*)(frc + voff);
        float g1[4], g2[4];
#pragma unroll
        for (int i = 0; i < 4; ++i) {
            g1[i] = *(const float*)(f1c + co[0][i]);
            g2[i] = *(const float*)(f2c + co[1][i]);
        }
        float w = wreg[c];
        float wr = w * r;
        r2 = fmaf(wr, r, r2);
        float wg1[4], wg2[4];
#pragma unroll
        for (int i = 0; i < 4; ++i) { wg1[i] = w * g1[i]; wg2[i] = w * g2[i]; }
#pragma unroll
        for (int i = 0; i < 4; ++i) {
            R1[i] = fmaf(wr, g1[i], R1[i]);
            R2[i] = fmaf(wr, g2[i], R2[i]);
        }
#pragma unroll
        for (int i = 0; i < 4; ++i)
#pragma unroll
            for (int j = i; j < 4; ++j) {
                G1[SYM(i, j)] = fmaf(wg1[i], g1[j], G1[SYM(i, j)]);
                G2[SYM(i, j)] = fmaf(wg2[i], g2[j], G2[SYM(i, j)]);
            }
#pragma unroll
        for (int i = 0; i < 4; ++i)
#pragma unroll
            for (int j = 0; j < 4; ++j)
                Cm[i * 4 + j] = fmaf(wg1[i], g2[j], Cm[i * 4 + j]);
    }
#pragma unroll
    for (int i = 0; i < 4; ++i)
#pragma unroll
        for (int j = i + 1; j < 4; ++j) {
            G1[SYM(i, j)] += G1[SYM(i, j)];
            G2[SYM(i, j)] += G2[SYM(i, j)];
        }

#pragma unroll
    for (int ck = 0; ck < DG / CHF; ++ck) {
        float pxs[2][CHF], pys[2][CHF];
#pragma unroll
        for (int dd = 0; dd < CHF; ++dd) {
            const float depth = *(const float*)((const char*)dvals +
                                 (size_t)(d0 + ck * CHF + dd) * HW * 4 + voff);
#pragma unroll
            for (int v = 0; v < 2; ++v) {
                float pxn = fmaf(rxv[v], depth, t0v[v]);
                float pyn = fmaf(ryv[v], depth, t1v[v]);
                float z   = fmaf(rzv[v], depth, t2v[v]);
                z = (fabsf(z) < 1e-6f) ? 1e-6f : z;
                pxs[v][dd] = pxn / z;
                pys[v][dd] = pyn / z;
            }
        }
#pragma unroll
        for (int dd = 0; dd < CHF; ++dd) {
            float al[2][4];
            int ax0[2], ay0[2];
            bool fast = true;
#pragma unroll
            for (int v = 0; v < 2; ++v) {
                float px = pxs[v][dd], py = pys[v][dd];
                float x0f = floorf(px), y0f = floorf(py);
                float wx = px - x0f, wy = py - y0f;
                int x0 = (int)x0f, y0 = (int)y0f;
                ax0[v] = x0; ay0[v] = y0;
                fast = fast && (x0 == x0r[v]) && (y0 == y0r[v]);
                bool vx0 = (x0 >= 0) && (x0 < NW);
                bool vx1 = (x0 + 1 >= 0) && (x0 + 1 < NW);
                bool vy0 = (y0 >= 0) && (y0 < NH);
                bool vy1 = (y0 + 1 >= 0) && (y0 + 1 < NH);
                al[v][0] = (1.f - wx) * (1.f - wy) * ((vx0 && vy0) ? 1.f : 0.f);
                al[v][1] = wx * (1.f - wy) * ((vx1 && vy0) ? 1.f : 0.f);
                al[v][2] = (1.f - wx) * wy * ((vx0 && vy1) ? 1.f : 0.f);
                al[v][3] = wx * wy * ((vx1 && vy1) ? 1.f : 0.f);
            }

            float cst;
            if (fast) {
                float q1 = 0.f, q2 = 0.f;
#pragma unroll
                for (int i = 0; i < 4; ++i)
#pragma unroll
                    for (int j = i; j < 4; ++j) {
                        q1 = fmaf(G1[SYM(i, j)], al[0][i] * al[0][j], q1);
                        q2 = fmaf(G2[SYM(i, j)], al[1][i] * al[1][j], q2);
                    }
                float qc = 0.f;
#pragma unroll
                for (int i = 0; i < 4; ++i)
#pragma unroll
                    for (int j = 0; j < 4; ++j)
                        qc = fmaf(Cm[i * 4 + j], al[0][i] * al[1][j], qc);
                float lr = 0.f;
#pragma unroll
                for (int i = 0; i < 4; ++i) {
                    lr = fmaf(R1[i], al[0][i], lr);
                    lr = fmaf(R2[i], al[1][i], lr);
                }
                cst = (2.f / 9.f) * (r2 + q1 + q2 - lr - qc);
            } else {
                unsigned so[2][4];
#pragma unroll
                for (int v = 0; v < 2; ++v) {
                    int cx0 = min(max(ax0[v], 0), NW - 1);
                    int cx1 = min(max(ax0[v] + 1, 0), NW - 1);
                    int cy0 = min(max(ay0[v], 0), NH - 1);
                    int cy1 = min(max(ay0[v] + 1, 0), NH - 1);
                    so[v][0] = (unsigned)(cy0 * NW + cx0) * 4u;
                    so[v][1] = (unsigned)(cy0 * NW + cx1) * 4u;
                    so[v][2] = (unsigned)(cy1 * NW + cx0) * 4u;
                    so[v][3] = (unsigned)(cy1 * NW + cx1) * 4u;
                }
                float acc = 0.f;
#pragma unroll
                for (int c = 0; c < NC; ++c) {
                    const char* frc = (const char*)feats + (size_t)c * HW * 4;
                    const char* f1c = f1b + (size_t)c * HW * 4;
                    const char* f2c = f2b + (size_t)c * HW * 4;
                    float r = *(const float*)(frc + voff);
                    float s1 = 0.f, s2 = 0.f;
#pragma unroll
                    for (int i = 0; i < 4; ++i) {
                        s1 = fmaf(*(const float*)(f1c + so[0][i]), al[0][i], s1);
                        s2 = fmaf(*(const float*)(f2c + so[1][i]), al[1][i], s2);
                    }
                    float e = r * r + s1 * s1 + s2 * s2
                            - r * s1 - r * s2 - s1 * s2;
                    acc = fmaf(wreg[c], e, acc);
                }
                cst = (2.f / 9.f) * acc;
            }
            *(float*)((char*)cost +
                      (size_t)(d0 + ck * CHF + dd) * HW * 4 + voff) = cst;
        }
    }
}

// ---------------------------------------------------------------------------
// Softmax over D + depth regression + confidence.
// ---------------------------------------------------------------------------
__global__ __launch_bounds__(256) void softmax_kernel(
    const float* __restrict__ dvals,
    float* __restrict__ out)
{
    int n = blockIdx.x * blockDim.x + threadIdx.x;
    float* prob = out + 2 * HW;

    float c[ND];
    float mx = -INFINITY;
#pragma unroll
    for (int d = 0; d < ND; ++d) {
        c[d] = prob[d * HW + n];
        mx = fmaxf(mx, c[d]);
    }
    float ssum = 0.f;
#pragma unroll
    for (int d = 0; d < ND; ++d) {
        float e = expf(c[d] - mx);
        c[d] = e;
        ssum += e;
    }
    float inv = 1.f / ssum;
    float depth_acc = 0.f, didx_acc = 0.f;
#pragma unroll
    for (int d = 0; d < ND; ++d) {
        float pv = c[d] * inv;
        c[d] = pv;
        prob[d * HW + n] = pv;
        depth_acc += pv * dvals[d * HW + n];
        didx_acc += pv * (float)d;
    }
    int di = (int)didx_acc;
    di = min(max(di, 0), ND - 1);
    float pdi = 0.f, pdi1 = 0.f;
#pragma unroll
    for (int d = 0; d < ND; ++d) {
        pdi = (d == di) ? c[d] : pdi;
        pdi1 = (d == di + 1) ? c[d] : pdi1;
    }
    out[n] = depth_acc;
    out[HW + n] = pdi + pdi1;
}

extern "C" void kernel_launch(void* const* d_in, const int* in_sizes, int n_in,
                              void* d_out, int out_size, void* d_ws, size_t ws_size,
                              hipStream_t stream) {
    const float* feats = (const float*)d_in[0];
    const float* pm    = (const float*)d_in[1];
    const float* dvals = (const float*)d_in[2];
    const float* wreg  = (const float*)d_in[3];
    float* out = (float*)d_out;
    float* mats = (float*)d_ws;                  // 24 floats

    proj_setup_kernel<<<1, 64, 0, stream>>>(pm, mats);

    if (ws_size >= COEF_OFF + COEF_BYTES) {
        float* coef = (float*)((char*)d_ws + COEF_OFF);
        stats_kernel<<<HW / 64, 64, 0, stream>>>(feats, dvals, wreg, mats,
                                                 coef);
        eval_kernel<<<dim3(HW / 256, ND / DGE), 256, 0, stream>>>(
            feats, dvals, wreg, mats, coef, out + 2 * HW);
    } else {
        cost_kernel9<<<dim3(HW / 256, ND / DG), 256, 0, stream>>>(
            feats, dvals, wreg, mats, out + 2 * HW);
    }
    softmax_kernel<<<HW / 256, 256, 0, stream>>>(dvals, out);
}